// Round 10
// baseline (798.266 us; speedup 1.0000x reference)
//
#include <hip/hip_runtime.h>
#include <hip/hip_bf16.h>

typedef __attribute__((ext_vector_type(8))) short bf16x8;
typedef __attribute__((ext_vector_type(4))) float f32x4;

#define NE 8192
#define MT 32
#define DD 256
#define NAPP 262144
#define NSLOT (NE*MT)
#define NSYM 50000
#define NSYMP 50048
#define TPB 8

// ws layout (bytes)
#define WS_WINNER 0
#define WS_WTSW   (1u<<20)
#define WS_WTLIN  (2u<<20)
#define WS_WFRAG  (3u<<20)   // 512KB frag-major Wg1/Wc1 (k<256)
#define WS_SYMGC  (4u<<20)   // NSYMP*512*2B = 51.2MB

static __device__ __forceinline__ unsigned short f2b(float x){
  union{float f; unsigned u;} v; v.f = x;
  unsigned r = (v.u + 0x7fffu + ((v.u>>16)&1u))>>16;
  return (unsigned short)r;
}
static __device__ __forceinline__ unsigned pk2(float a, float b){
  return (unsigned)f2b(a) | ((unsigned)f2b(b)<<16);
}
static __device__ __forceinline__ unsigned pkc(float a, float b){
  union { __hip_bfloat162 h; unsigned u; } c;
  c.h = __float22bfloat162_rn(float2{a, b});
  return c.u;
}
static __device__ __forceinline__ float frombf(unsigned short u){ union{unsigned x; float f;} v; v.x = ((unsigned)u)<<16; return v.f; }

static __device__ __forceinline__ void gload16(const void* g, void* l){
  __builtin_amdgcn_global_load_lds((const __attribute__((address_space(1))) void*)g,
                                   (__attribute__((address_space(3))) void*)l, 16, 0, 0);
}

// ---- K0: weights f32 [512][256] -> bf16: wtsw (pre-swizzled, k_syms), wtlin (k_gate2),
// wfrag (frag-major for k_gate1: ((m*32+cg)*8+kt)*1024 + ((n&15)*4+(kg&3))*16, k<256, m<2)
__global__ void k_wt(const float* __restrict__ w0, const float* __restrict__ w1,
                     const float* __restrict__ w2, const float* __restrict__ w3,
                     char* __restrict__ wtsw, unsigned short* __restrict__ wtlin,
                     char* __restrict__ wfrag){
  int g = blockIdx.x*256 + threadIdx.x;   // m(2) kg(6) n(8)
  int m = g >> 14;
  int kg = (g >> 8) & 63;
  int n = g & 255;
  const float* W = (m==0)?w0:(m==1)?w1:(m==2)?w2:w3;
  unsigned short v[8];
  #pragma unroll
  for (int i=0;i<8;i++) v[i] = f2b(W[(kg*8+i)*DD + n]);
  uint4 u;
  u.x = (unsigned)v[0] | ((unsigned)v[1]<<16);
  u.y = (unsigned)v[2] | ((unsigned)v[3]<<16);
  u.z = (unsigned)v[4] | ((unsigned)v[5]<<16);
  u.w = (unsigned)v[6] | ((unsigned)v[7]<<16);
  *(uint4*)(wtlin + (size_t)m*131072 + n*512 + kg*8) = u;
  int rot = ((kg & 3) + (n >> 1)) & 3;
  *(uint4*)(wtsw + (size_t)m*262144 + n*1024 + (kg>>2)*64 + rot*16) = u;
  if (m < 2 && kg < 32){
    size_t fa = ((size_t)((m*32 + (n>>4))*8 + (kg>>2)) << 10) + (size_t)(((n&15)*4 + (kg&3)) << 4);
    *(uint4*)(wfrag + fa) = u;
  }
}

// ---- K1: last-write-wins winner per slot
__global__ void k_winner(const int* __restrict__ ei, const int* __restrict__ ti,
                         int* __restrict__ winner){
  int i = blockIdx.x*256 + threadIdx.x;
  atomicMax(&winner[ei[i]*MT + ti[i]], i);
}

// ---- K_syms: SymGC[s] = sym[s] @ [Wg1_bot | Wc1_bot] (bf16), interleaved (validated R6)
__global__ __launch_bounds__(512, 4)
void k_syms(const float* __restrict__ sym, const char* __restrict__ wtsw,
            unsigned short* __restrict__ symgc){
  __shared__ char Abuf[32768];
  __shared__ char Bbuf[32768];

  int tid = threadIdx.x, lane = tid & 63, wv = tid >> 6;
  int l15 = lane & 15, lg = lane >> 4;
  int wq = wv & 3; bool isC = wv >= 4;
  int s0 = blockIdx.x * 64;

  {
    int r = tid >> 3;
    int row = s0 + r;
    char* arow = Abuf + r*512;
    unsigned swz = (unsigned)((r & 15) << 4);
    if (row < NSYM){
      const float* src = sym + (size_t)row*DD;
      #pragma unroll
      for (int i=0;i<4;i++){
        int c = (tid & 7) + i*8;
        float4 x = *(const float4*)(src + c*8);
        float4 y = *(const float4*)(src + c*8 + 4);
        uint4 u; u.x=pk2(x.x,x.y); u.y=pk2(x.z,x.w); u.z=pk2(y.x,y.y); u.w=pk2(y.z,y.w);
        *(uint4*)(arow + ((c*16) ^ swz)) = u;
      }
    } else {
      uint4 u = {0,0,0,0};
      #pragma unroll
      for (int i=0;i<4;i++){
        int c = (tid & 7) + i*8;
        *(uint4*)(arow + ((c*16) ^ swz)) = u;
      }
    }
  }
  __syncthreads();

  f32x4 acc[4][4];
  f32x4 zz = {0.f,0.f,0.f,0.f};
  #pragma unroll
  for (int rt=0;rt<4;rt++)
    #pragma unroll
    for (int ct=0;ct<4;ct++) acc[rt][ct]=zz;

  const char* wbG = wtsw;
  const char* wbC = wtsw + 262144;

  for (int kt=0; kt<8; ++kt){
    __syncthreads();
    #pragma unroll
    for (int i=0;i<4;i++){
      int n = wv*64 + i*16 + (lane>>2);
      const char* src = ((n < 256)? wbG : wbC) + (size_t)(n & 255)*1024 + (8+kt)*64 + (lane&3)*16;
      gload16(src, Bbuf + n*64 + (lane&3)*16);
    }
    __syncthreads();
    int koff = kt*64 + lg*16;
    bf16x8 a[4], b[4];
    #pragma unroll
    for (int rt=0;rt<4;rt++)
      a[rt] = *(const bf16x8*)(Abuf + (rt*16 + l15)*512 + (koff ^ (l15<<4)));
    #pragma unroll
    for (int ct=0;ct<4;ct++){
      int nn = (isC?256:0) + wq*64 + ct*16 + l15;
      b[ct] = *(const bf16x8*)(Bbuf + nn*64 + (((lg + (nn>>1)) & 3)<<4));
    }
    #pragma unroll
    for (int rt=0;rt<4;rt++)
      #pragma unroll
      for (int ct=0;ct<4;ct++)
        acc[rt][ct] = __builtin_amdgcn_mfma_f32_16x16x32_bf16(a[rt], b[ct], acc[rt][ct], 0,0,0);
  }

  #pragma unroll
  for (int rt=0;rt<4;rt++)
    #pragma unroll
    for (int ct=0;ct<4;ct++)
      #pragma unroll
      for (int j=0;j<4;j++){
        int row = s0 + rt*16 + lg*4 + j;
        int idx = (wq*2 + (ct>>1))*64 + l15*4 + (ct&1)*2 + (isC?1:0);
        symgc[(size_t)row*512 + idx] = f2b(acc[rt][ct][j]);
      }
}

// ---- K2: gate1, persistent: 512 blocks x 8 tiles, 8 waves. Wave = 64 rows x 32 cols x
// both mats (acc 64). B: frag-major wfrag, depth-2 register ring, no LDS, no asm sync.
// A: bf16 dbuf 2x32KB, T14 reg-staged (loads 2 phases before cvt+ds_write_b64).
// One __syncthreads per tile.
__global__ __launch_bounds__(512, 4)
void k_gate1(const float* __restrict__ expr, const char* __restrict__ wfrag,
             const float* __restrict__ bg, const float* __restrict__ bc,
             const int* __restrict__ winner, const int* __restrict__ appsym,
             const unsigned short* __restrict__ symgc,
             float* __restrict__ outcomb){
  __shared__ char A2[2][32768];

  int tid = threadIdx.x, lane = tid & 63, wv = tid >> 6;
  int l15 = lane & 15, lg = lane >> 4;
  int base = blockIdx.x * TPB;

  int lofs = (l15*4 + lg) << 4;
  const char* wfw = wfrag + (size_t)(wv << 14);   // + mat*262144 + ct*8192 + kt*1024 + lofs

  float bgv[2], bcv[2];
  #pragma unroll
  for (int ct=0; ct<2; ++ct){
    int c = wv*32 + ct*16 + l15;
    bgv[ct] = bg[c]; bcv[ct] = bc[c];
  }

  // prime B ring: slot s holds frags of kt=s; q = mat*2+ct
  bf16x8 bR[2][4];
  #pragma unroll
  for (int s=0;s<2;s++)
    #pragma unroll
    for (int q=0;q<4;q++)
      bR[s][q] = *(const bf16x8*)(wfw + (q>>1)*262144 + (q&1)*8192 + s*1024 + lofs);

  // stage tile 0 into buf 0
  {
    const float* src = expr + (size_t)base*64*DD;
    #pragma unroll
    for (int i=0;i<8;i++){
      float4 v = *(const float4*)(src + i*2048 + tid*4);
      int ri = wv + 8*i;
      uint2 w; w.x = pkc(v.x, v.y); w.y = pkc(v.z, v.w);
      *(uint2*)(A2[0] + ri*512 + ((((lane>>1)<<4) ^ ((ri&15)<<4))) + ((lane&1)<<3)) = w;
    }
  }
  __syncthreads();

  for (int t=0; t<TPB; ++t){
    int cur = t & 1;
    int s0 = (base + t) * 64;

    int wn = winner[s0 + lane];
    int sidv = (wn >= 0) ? appsym[wn] : 0;
    unsigned long long hwmask = __ballot(wn >= 0);

    f32x4 accG[4][2], accC[4][2];
    f32x4 zz = {0.f,0.f,0.f,0.f};
    #pragma unroll
    for (int rt=0;rt<4;rt++){ accG[rt][0]=zz; accG[rt][1]=zz; accC[rt][0]=zz; accC[rt][1]=zz; }

    const char* pa = A2[cur];
    char* pn = A2[cur^1];
    const float* nsrc = expr + (size_t)(s0 + 64)*DD;
    bool more = (t < TPB-1);
    float4 L0, L1, L2, L3;   // staging regs, batches of 2

    #pragma unroll
    for (int kt=0; kt<8; ++kt){
      // staged loads for next tile (2 per even phase, used 2 phases later)
      if (more){
        if (kt == 0){ L0 = *(const float4*)(nsrc + tid*4);          L1 = *(const float4*)(nsrc + 2048 + tid*4); }
        if (kt == 2){ L2 = *(const float4*)(nsrc + 2*2048 + tid*4); L3 = *(const float4*)(nsrc + 3*2048 + tid*4); }
      }
      // A fragments
      bf16x8 a[4];
      #pragma unroll
      for (int rt=0;rt<4;rt++)
        a[rt] = *(const bf16x8*)(pa + (rt*16+l15)*512 + ((((kt*4+lg)<<4)) ^ (l15<<4)));
      // 16 MFMAs
      #pragma unroll
      for (int rt=0;rt<4;rt++){
        accG[rt][0] = __builtin_amdgcn_mfma_f32_16x16x32_bf16(a[rt], bR[kt&1][0], accG[rt][0], 0,0,0);
        accG[rt][1] = __builtin_amdgcn_mfma_f32_16x16x32_bf16(a[rt], bR[kt&1][1], accG[rt][1], 0,0,0);
        accC[rt][0] = __builtin_amdgcn_mfma_f32_16x16x32_bf16(a[rt], bR[kt&1][2], accC[rt][0], 0,0,0);
        accC[rt][1] = __builtin_amdgcn_mfma_f32_16x16x32_bf16(a[rt], bR[kt&1][3], accC[rt][1], 0,0,0);
      }
      // reload ring slot with kt+2 (weights identical every tile; wraps)
      {
        int kn = (kt+2)&7;
        #pragma unroll
        for (int q=0;q<4;q++)
          bR[kt&1][q] = *(const bf16x8*)(wfw + (q>>1)*262144 + (q&1)*8192 + kn*1024 + lofs);
      }
      // staged writes (cvt + b64; all lanes same row -> conflict-free)
      if (more){
        if (kt == 2){
          { int ri = wv;     uint2 w; w.x=pkc(L0.x,L0.y); w.y=pkc(L0.z,L0.w);
            *(uint2*)(pn + ri*512 + ((((lane>>1)<<4) ^ ((ri&15)<<4))) + ((lane&1)<<3)) = w; }
          { int ri = wv + 8; uint2 w; w.x=pkc(L1.x,L1.y); w.y=pkc(L1.z,L1.w);
            *(uint2*)(pn + ri*512 + ((((lane>>1)<<4) ^ ((ri&15)<<4))) + ((lane&1)<<3)) = w; }
        }
        if (kt == 4){
          { int ri = wv + 16; uint2 w; w.x=pkc(L2.x,L2.y); w.y=pkc(L2.z,L2.w);
            *(uint2*)(pn + ri*512 + ((((lane>>1)<<4) ^ ((ri&15)<<4))) + ((lane&1)<<3)) = w; }
          { int ri = wv + 24; uint2 w; w.x=pkc(L3.x,L3.y); w.y=pkc(L3.z,L3.w);
            *(uint2*)(pn + ri*512 + ((((lane>>1)<<4) ^ ((ri&15)<<4))) + ((lane&1)<<3)) = w; }
          L0 = *(const float4*)(nsrc + 4*2048 + tid*4);
          L1 = *(const float4*)(nsrc + 5*2048 + tid*4);
        }
        if (kt == 6){
          { int ri = wv + 32; uint2 w; w.x=pkc(L0.x,L0.y); w.y=pkc(L0.z,L0.w);
            *(uint2*)(pn + ri*512 + ((((lane>>1)<<4) ^ ((ri&15)<<4))) + ((lane&1)<<3)) = w; }
          { int ri = wv + 40; uint2 w; w.x=pkc(L1.x,L1.y); w.y=pkc(L1.z,L1.w);
            *(uint2*)(pn + ri*512 + ((((lane>>1)<<4) ^ ((ri&15)<<4))) + ((lane&1)<<3)) = w; }
          L2 = *(const float4*)(nsrc + 6*2048 + tid*4);
          L3 = *(const float4*)(nsrc + 7*2048 + tid*4);
        }
      }
    }
    if (more){
      { int ri = wv + 48; uint2 w; w.x=pkc(L2.x,L2.y); w.y=pkc(L2.z,L2.w);
        *(uint2*)(pn + ri*512 + ((((lane>>1)<<4) ^ ((ri&15)<<4))) + ((lane&1)<<3)) = w; }
      { int ri = wv + 56; uint2 w; w.x=pkc(L3.x,L3.y); w.y=pkc(L3.z,L3.w);
        *(uint2*)(pn + ri*512 + ((((lane>>1)<<4) ^ ((ri&15)<<4))) + ((lane&1)<<3)) = w; }
    }

    // ---- epilogue: in-register combine + token-mean (validated structure)
    float osum[2][2] = {{0.f,0.f},{0.f,0.f}};
    #pragma unroll
    for (int rt=0;rt<4;rt++){
      #pragma unroll
      for (int j=0;j<4;j++){
        int row = rt*16 + lg*4 + j;
        int sid = __shfl(sidv, row);
        const ushort4 sv = *(const ushort4*)(symgc + (size_t)sid*512 + wv*64 + l15*4);
        bool hw = (hwmask >> row) & 1ull;
        const float* prow = expr + (size_t)(s0+row)*DD;
        #pragma unroll
        for (int ct=0;ct<2;ct++){
          float p = prow[wv*32 + ct*16 + l15];
          float gl = accG[rt][ct][j] + frombf(ct ? sv.z : sv.x) + bgv[ct];
          float cl = accC[rt][ct][j] + frombf(ct ? sv.w : sv.y) + bcv[ct];
          float f = 1.f/(1.f + __expf(-gl));
          float cd = fmaxf(cl, 0.f);
          osum[rt>>1][ct] += hw ? (f*p + (1.f-f)*cd) : p;
        }
      }
    }
    #pragma unroll
    for (int e=0;e<2;e++)
      #pragma unroll
      for (int ct=0;ct<2;ct++){
        float s = osum[e][ct];
        s += __shfl_xor(s, 16);
        s += __shfl_xor(s, 32);
        if (lane < 16)
          outcomb[(size_t)((base+t)*2 + e)*DD + wv*32 + ct*16 + l15] = s * (1.f/32.f);
      }
    __syncthreads();
  }
}

// ---- K3: gate2 over 64 expressions per block, in-place on d_out (validated; uses wt_lin)
__global__ __launch_bounds__(1024)
void k_gate2(const float* __restrict__ prevn, const float* comb,
             const float* __restrict__ bg, const float* __restrict__ bc,
             const unsigned short* __restrict__ Wgt, const unsigned short* __restrict__ Wct,
             float* out){
  __shared__ char A[64*1024];

  int tid  = threadIdx.x;
  int lane = tid & 63;
  int wv   = tid >> 6;
  int wr = wv >> 3, wc = wv & 7;
  int l15 = lane & 15, lg = lane >> 4;
  int e0 = blockIdx.x * 64;

  {
    int row = tid >> 4, cb = (tid & 15)*16;
    unsigned swz = (unsigned)((row&7)<<4);
    const float* src = prevn + (size_t)(e0+row)*DD + cb;
    const float* s2  = comb  + (size_t)(e0+row)*DD + cb;
    char* arow = A + row*1024;
    #pragma unroll
    for (int i=0;i<2;i++){
      float4 x = *(const float4*)(src + i*8);
      float4 y = *(const float4*)(src + i*8 + 4);
      uint4 u; u.x=pk2(x.x,x.y); u.y=pk2(x.z,x.w); u.z=pk2(y.x,y.y); u.w=pk2(y.z,y.w);
      *(uint4*)(arow + (((cb+i*8)*2) ^ swz)) = u;
    }
    #pragma unroll
    for (int i=0;i<2;i++){
      float4 x = *(const float4*)(s2 + i*8);
      float4 y = *(const float4*)(s2 + i*8 + 4);
      uint4 u; u.x=pk2(x.x,x.y); u.y=pk2(x.z,x.w); u.z=pk2(y.x,y.y); u.w=pk2(y.z,y.w);
      *(uint4*)(arow + (((256+cb+i*8)*2) ^ swz)) = u;
    }
  }
  __syncthreads();

  unsigned swzL = (unsigned)((l15&7)<<4);
  const char* pa0 = A + (wr*32 + l15)*1024;
  const char* pa1 = pa0 + 16*1024;
  const unsigned short* wg0 = Wgt + (size_t)(wc*32 + l15)*512 + lg*8;
  const unsigned short* wc0 = Wct + (size_t)(wc*32 + l15)*512 + lg*8;

  f32x4 accg[2][2], accc[2][2];
  f32x4 zz = {0.f,0.f,0.f,0.f};
  #pragma unroll
  for (int ri=0;ri<2;ri++){ accg[ri][0]=zz; accg[ri][1]=zz; accc[ri][0]=zz; accc[ri][1]=zz; }

  for (int ks=0; ks<16; ++ks){
    int koff = (ks*64 + lg*16) ^ (int)swzL;
    bf16x8 a0 = *(const bf16x8*)(pa0 + koff);
    bf16x8 a1 = *(const bf16x8*)(pa1 + koff);
    int kw = ks*32;
    #pragma unroll
    for (int ct=0; ct<2; ++ct){
      bf16x8 b = *(const bf16x8*)(wg0 + ct*16*512 + kw);
      accg[0][ct] = __builtin_amdgcn_mfma_f32_16x16x32_bf16(a0, b, accg[0][ct], 0,0,0);
      accg[1][ct] = __builtin_amdgcn_mfma_f32_16x16x32_bf16(a1, b, accg[1][ct], 0,0,0);
    }
  }

  float bgv[2], bcv[2];
  #pragma unroll
  for (int ct=0;ct<2;ct++){ int c = wc*32+ct*16+l15; bgv[ct]=bg[c]; bcv[ct]=bc[c]; }
  #pragma unroll
  for (int ri=0;ri<2;ri++)
    #pragma unroll
    for (int ct=0;ct<2;ct++)
      #pragma unroll
      for (int j=0;j<4;j++)
        accg[ri][ct][j] = 1.f/(1.f + __expf(-(accg[ri][ct][j] + bgv[ct])));

  for (int ks=0; ks<16; ++ks){
    int koff = (ks*64 + lg*16) ^ (int)swzL;
    bf16x8 a0 = *(const bf16x8*)(pa0 + koff);
    bf16x8 a1 = *(const bf16x8*)(pa1 + koff);
    int kw = ks*32;
    #pragma unroll
    for (int ct=0; ct<2; ++ct){
      bf16x8 b = *(const bf16x8*)(wc0 + ct*16*512 + kw);
      accc[0][ct] = __builtin_amdgcn_mfma_f32_16x16x32_bf16(a0, b, accc[0][ct], 0,0,0);
      accc[1][ct] = __builtin_amdgcn_mfma_f32_16x16x32_bf16(a1, b, accc[1][ct], 0,0,0);
    }
  }

  #pragma unroll
  for (int ct=0; ct<2; ++ct){
    #pragma unroll
    for (int ri=0; ri<2; ++ri){
      #pragma unroll
      for (int j=0;j<4;j++){
        int row = wr*32 + ri*16 + lg*4 + j;
        int col = wc*32 + ct*16 + l15;
        int e = e0 + row;
        float prevv = prevn[(size_t)e*DD + col];
        float fr = accg[ri][ct][j];
        float cand = fmaxf(accc[ri][ct][j] + bcv[ct], 0.f);
        out[(size_t)e*DD + col] = fr*prevv + (1.f-fr)*cand;
      }
    }
  }
}

extern "C" void kernel_launch(void* const* d_in, const int* in_sizes, int n_in,
                              void* d_out, int out_size, void* d_ws, size_t ws_size,
                              hipStream_t stream){
  const float* expr = (const float*)d_in[0];
  const float* sym  = (const float*)d_in[1];
  const float* prevn= (const float*)d_in[2];
  const float* Wg1 = (const float*)d_in[3];
  const float* bg1 = (const float*)d_in[4];
  const float* Wc1 = (const float*)d_in[5];
  const float* bc1 = (const float*)d_in[6];
  const float* Wg2 = (const float*)d_in[7];
  const float* bg2 = (const float*)d_in[8];
  const float* Wc2 = (const float*)d_in[9];
  const float* bc2 = (const float*)d_in[10];
  const int* aei = (const int*)d_in[11];
  const int* ati = (const int*)d_in[12];
  const int* asi = (const int*)d_in[13];
  float* outp = (float*)d_out;

  char* wsb = (char*)d_ws;
  int* winner = (int*)(wsb + WS_WINNER);
  char* wtsw = wsb + WS_WTSW;
  unsigned short* wtlin = (unsigned short*)(wsb + WS_WTLIN);
  char* wfrag = wsb + WS_WFRAG;
  unsigned short* symgc = (unsigned short*)(wsb + WS_SYMGC);

  hipMemsetAsync(winner, 0xFF, NSLOT*sizeof(int), stream);
  k_wt<<<256, 256, 0, stream>>>(Wg1, Wc1, Wg2, Wc2, wtsw, wtlin, wfrag);
  k_winner<<<NAPP/256, 256, 0, stream>>>(aei, ati, winner);
  k_syms<<<NSYMP/64, 512, 0, stream>>>(sym, wtsw, symgc);
  k_gate1<<<NSLOT/(64*TPB), 512, 0, stream>>>(expr, wfrag, bg1, bc1, winner, asi, symgc, outp);
  k_gate2<<<NE/64, 1024, 0, stream>>>(prevn, outp, bg2, bc2,
                                      wtlin + 262144, wtlin + 393216, outp);
}

// Round 11
// 356.694 us; speedup vs baseline: 2.2380x; 2.2380x over previous
//
#include <hip/hip_runtime.h>
#include <hip/hip_bf16.h>

typedef __attribute__((ext_vector_type(8))) short bf16x8;
typedef __attribute__((ext_vector_type(4))) float f32x4;

#define NE 8192
#define MT 32
#define DD 256
#define NAPP 262144
#define NSLOT (NE*MT)
#define NSYM 50000
#define NSYMP 50048

// ws layout (bytes)
#define WS_WINNER 0
#define WS_WTSW   (1u<<20)
#define WS_WTLIN  (2u<<20)
#define WS_SYMGC  (3u<<20)   // NSYMP*512*2B = 51.2MB

static __device__ __forceinline__ unsigned short f2b(float x){
  union{float f; unsigned u;} v; v.f = x;
  unsigned r = (v.u + 0x7fffu + ((v.u>>16)&1u))>>16;
  return (unsigned short)r;
}
static __device__ __forceinline__ unsigned pk2(float a, float b){
  return (unsigned)f2b(a) | ((unsigned)f2b(b)<<16);
}
static __device__ __forceinline__ float frombf(unsigned short u){ union{unsigned x; float f;} v; v.x = ((unsigned)u)<<16; return v.f; }

static __device__ __forceinline__ void gload16(const void* g, void* l){
  __builtin_amdgcn_global_load_lds((const __attribute__((address_space(1))) void*)g,
                                   (__attribute__((address_space(3))) void*)l, 16, 0, 0);
}

// ---- K0: weights f32 [512][256] -> bf16 transposed, two copies (pre-swizzled + linear)
__global__ void k_wt(const float* __restrict__ w0, const float* __restrict__ w1,
                     const float* __restrict__ w2, const float* __restrict__ w3,
                     char* __restrict__ wtsw, unsigned short* __restrict__ wtlin){
  int g = blockIdx.x*256 + threadIdx.x;   // m(2) kg(6) n(8)
  int m = g >> 14;
  int kg = (g >> 8) & 63;
  int n = g & 255;
  const float* W = (m==0)?w0:(m==1)?w1:(m==2)?w2:w3;
  unsigned short v[8];
  #pragma unroll
  for (int i=0;i<8;i++) v[i] = f2b(W[(kg*8+i)*DD + n]);
  uint4 u;
  u.x = (unsigned)v[0] | ((unsigned)v[1]<<16);
  u.y = (unsigned)v[2] | ((unsigned)v[3]<<16);
  u.z = (unsigned)v[4] | ((unsigned)v[5]<<16);
  u.w = (unsigned)v[6] | ((unsigned)v[7]<<16);
  *(uint4*)(wtlin + (size_t)m*131072 + n*512 + kg*8) = u;
  int rot = ((kg & 3) + (n >> 1)) & 3;
  *(uint4*)(wtsw + (size_t)m*262144 + n*1024 + (kg>>2)*64 + rot*16) = u;
}

// ---- K1: last-write-wins winner per slot
__global__ void k_winner(const int* __restrict__ ei, const int* __restrict__ ti,
                         int* __restrict__ winner){
  int i = blockIdx.x*256 + threadIdx.x;
  atomicMax(&winner[ei[i]*MT + ti[i]], i);
}

// ---- K_syms: SymGC[s] = sym[s] @ [Wg1_bot | Wc1_bot] (bf16), interleaved (validated R6)
__global__ __launch_bounds__(512, 4)
void k_syms(const float* __restrict__ sym, const char* __restrict__ wtsw,
            unsigned short* __restrict__ symgc){
  __shared__ char Abuf[32768];
  __shared__ char Bbuf[32768];

  int tid = threadIdx.x, lane = tid & 63, wv = tid >> 6;
  int l15 = lane & 15, lg = lane >> 4;
  int wq = wv & 3; bool isC = wv >= 4;
  int s0 = blockIdx.x * 64;

  {
    int r = tid >> 3;
    int row = s0 + r;
    char* arow = Abuf + r*512;
    unsigned swz = (unsigned)((r & 15) << 4);
    if (row < NSYM){
      const float* src = sym + (size_t)row*DD;
      #pragma unroll
      for (int i=0;i<4;i++){
        int c = (tid & 7) + i*8;
        float4 x = *(const float4*)(src + c*8);
        float4 y = *(const float4*)(src + c*8 + 4);
        uint4 u; u.x=pk2(x.x,x.y); u.y=pk2(x.z,x.w); u.z=pk2(y.x,y.y); u.w=pk2(y.z,y.w);
        *(uint4*)(arow + ((c*16) ^ swz)) = u;
      }
    } else {
      uint4 u = {0,0,0,0};
      #pragma unroll
      for (int i=0;i<4;i++){
        int c = (tid & 7) + i*8;
        *(uint4*)(arow + ((c*16) ^ swz)) = u;
      }
    }
  }
  __syncthreads();

  f32x4 acc[4][4];
  f32x4 zz = {0.f,0.f,0.f,0.f};
  #pragma unroll
  for (int rt=0;rt<4;rt++)
    #pragma unroll
    for (int ct=0;ct<4;ct++) acc[rt][ct]=zz;

  const char* wbG = wtsw;
  const char* wbC = wtsw + 262144;

  for (int kt=0; kt<8; ++kt){
    __syncthreads();
    #pragma unroll
    for (int i=0;i<4;i++){
      int n = wv*64 + i*16 + (lane>>2);
      const char* src = ((n < 256)? wbG : wbC) + (size_t)(n & 255)*1024 + (8+kt)*64 + (lane&3)*16;
      gload16(src, Bbuf + n*64 + (lane&3)*16);
    }
    __syncthreads();
    int koff = kt*64 + lg*16;
    bf16x8 a[4], b[4];
    #pragma unroll
    for (int rt=0;rt<4;rt++)
      a[rt] = *(const bf16x8*)(Abuf + (rt*16 + l15)*512 + (koff ^ (l15<<4)));
    #pragma unroll
    for (int ct=0;ct<4;ct++){
      int nn = (isC?256:0) + wq*64 + ct*16 + l15;
      b[ct] = *(const bf16x8*)(Bbuf + nn*64 + (((lg + (nn>>1)) & 3)<<4));
    }
    #pragma unroll
    for (int rt=0;rt<4;rt++)
      #pragma unroll
      for (int ct=0;ct<4;ct++)
        acc[rt][ct] = __builtin_amdgcn_mfma_f32_16x16x32_bf16(a[rt], b[ct], acc[rt][ct], 0,0,0);
  }

  #pragma unroll
  for (int rt=0;rt<4;rt++)
    #pragma unroll
    for (int ct=0;ct<4;ct++)
      #pragma unroll
      for (int j=0;j<4;j++){
        int row = s0 + rt*16 + lg*4 + j;
        int idx = (wq*2 + (ct>>1))*64 + l15*4 + (ct&1)*2 + (isC?1:0);
        symgc[(size_t)row*512 + idx] = f2b(acc[rt][ct][j]);
      }
}

// ---- K2: gate1. 8192 blocks (1 expression each) x 256 thr (4 waves); 3 blocks/CU
// (48KB LDS) = 3 independent barrier domains per CU for block-level TLP.
// Wave wv = 32 rows x 64 cols (wv*64..+63) x both mats; acc 64 regs.
// A [32][256] bf16 16KB staged once; B slab (512 flat cols x BK=32) 32KB re-staged
// per kt via global_load_lds from pre-rotated wtsw; stage->sync->compute->sync.
__global__ __launch_bounds__(256, 3)
void k_gate1(const float* __restrict__ expr, const char* __restrict__ wtsw,
             const float* __restrict__ bg, const float* __restrict__ bc,
             const int* __restrict__ winner, const int* __restrict__ appsym,
             const unsigned short* __restrict__ symgc,
             float* __restrict__ outcomb){
  __shared__ char Abuf[16384];   // [32 rows][512B], chunk ^ ((r&15)<<4)
  __shared__ char Bb[32768];     // [2 mats][256 n][64B], rot pre-baked

  int tid = threadIdx.x, lane = tid & 63, wv = tid >> 6;  // wv 0..3
  int l15 = lane & 15, lg = lane >> 4;
  int s0 = blockIdx.x * 32;

  int wn = (lane < 32) ? winner[s0 + lane] : -1;
  int sidv = (wn >= 0) ? appsym[wn] : 0;
  unsigned long long hwmask = __ballot(wn >= 0);   // bits 0..31

  float bgv[4], bcv[4];
  #pragma unroll
  for (int ct=0; ct<4; ++ct){
    int c = wv*64 + ct*16 + l15;
    bgv[ct] = bg[c]; bcv[ct] = bc[c];
  }

  { // stage A rows 0..31 (8 threads/row, 4 chunks each)
    int r = tid >> 3;
    const float* src = expr + (size_t)(s0 + r)*DD;
    char* arow = Abuf + r*512;
    unsigned swz = (unsigned)((r & 15) << 4);
    #pragma unroll
    for (int i=0;i<4;i++){
      int c = (tid & 7) + i*8;
      float4 x = *(const float4*)(src + c*8);
      float4 y = *(const float4*)(src + c*8 + 4);
      uint4 u; u.x=pk2(x.x,x.y); u.y=pk2(x.z,x.w); u.z=pk2(y.x,y.y); u.w=pk2(y.z,y.w);
      *(uint4*)(arow + ((c*16) ^ swz)) = u;
    }
  }

  f32x4 accG[2][4], accC[2][4];
  f32x4 zz = {0.f,0.f,0.f,0.f};
  #pragma unroll
  for (int rt=0;rt<2;rt++)
    #pragma unroll
    for (int ct=0;ct<4;ct++){ accG[rt][ct]=zz; accC[rt][ct]=zz; }

  for (int kt=0; kt<8; ++kt){
    __syncthreads();   // prior compute done (and on kt=0: A-stage visible)
    #pragma unroll
    for (int i=0;i<8;i++){
      int g = tid + i*256;               // 0..2047 -> mat(1) n(8) p(2)
      int mat = g >> 10, n = (g >> 2) & 255, p = g & 3;
      gload16(wtsw + (size_t)mat*262144 + (size_t)n*1024 + kt*64 + p*16, Bb + g*16);
    }
    __syncthreads();   // drains vmcnt(0) -> slab + A visible
    int koff = (kt*4 + lg) << 4;
    bf16x8 a[2];
    #pragma unroll
    for (int rt=0;rt<2;rt++)
      a[rt] = *(const bf16x8*)(Abuf + (rt*16 + l15)*512 + (koff ^ (l15<<4)));
    #pragma unroll
    for (int ct=0;ct<4;ct++){
      int n = wv*64 + ct*16 + l15;
      int ro = ((lg + (n>>1)) & 3) << 4;
      bf16x8 bG = *(const bf16x8*)(Bb + n*64 + ro);
      bf16x8 bC = *(const bf16x8*)(Bb + 16384 + n*64 + ro);
      #pragma unroll
      for (int rt=0;rt<2;rt++){
        accG[rt][ct] = __builtin_amdgcn_mfma_f32_16x16x32_bf16(a[rt], bG, accG[rt][ct], 0,0,0);
        accC[rt][ct] = __builtin_amdgcn_mfma_f32_16x16x32_bf16(a[rt], bC, accC[rt][ct], 0,0,0);
      }
    }
  }

  // ---- epilogue: in-register combine + token-mean over the block's 32 rows
  float osum[4] = {0.f,0.f,0.f,0.f};
  #pragma unroll
  for (int rt=0;rt<2;rt++){
    #pragma unroll
    for (int j=0;j<4;j++){
      int row = rt*16 + lg*4 + j;       // 0..31
      int sid = __shfl(sidv, row);
      bool hw = (hwmask >> row) & 1ull;
      const ushort4 svA = *(const ushort4*)(symgc + (size_t)sid*512 + wv*128 + l15*4);
      const ushort4 svB = *(const ushort4*)(symgc + (size_t)sid*512 + wv*128 + 64 + l15*4);
      const float* prow = expr + (size_t)(s0+row)*DD;
      #pragma unroll
      for (int ct=0;ct<4;ct++){
        float p = prow[wv*64 + ct*16 + l15];
        unsigned short gs = (ct==0)?svA.x:(ct==1)?svA.z:(ct==2)?svB.x:svB.z;
        unsigned short cs = (ct==0)?svA.y:(ct==1)?svA.w:(ct==2)?svB.y:svB.w;
        float gl = accG[rt][ct][j] + frombf(gs) + bgv[ct];
        float cl = accC[rt][ct][j] + frombf(cs) + bcv[ct];
        float f = 1.f/(1.f + __expf(-gl));
        float cd = fmaxf(cl, 0.f);
        osum[ct] += hw ? (f*p + (1.f-f)*cd) : p;
      }
    }
  }
  #pragma unroll
  for (int ct=0;ct<4;ct++){
    float s = osum[ct];
    s += __shfl_xor(s, 16);
    s += __shfl_xor(s, 32);
    if (lane < 16)
      outcomb[(size_t)blockIdx.x*DD + wv*64 + ct*16 + l15] = s * (1.f/32.f);
  }
}

// ---- K3: gate2 over 64 expressions per block, in-place on d_out (validated; uses wt_lin)
__global__ __launch_bounds__(1024)
void k_gate2(const float* __restrict__ prevn, const float* comb,
             const float* __restrict__ bg, const float* __restrict__ bc,
             const unsigned short* __restrict__ Wgt, const unsigned short* __restrict__ Wct,
             float* out){
  __shared__ char A[64*1024];

  int tid  = threadIdx.x;
  int lane = tid & 63;
  int wv   = tid >> 6;
  int wr = wv >> 3, wc = wv & 7;
  int l15 = lane & 15, lg = lane >> 4;
  int e0 = blockIdx.x * 64;

  {
    int row = tid >> 4, cb = (tid & 15)*16;
    unsigned swz = (unsigned)((row&7)<<4);
    const float* src = prevn + (size_t)(e0+row)*DD + cb;
    const float* s2  = comb  + (size_t)(e0+row)*DD + cb;
    char* arow = A + row*1024;
    #pragma unroll
    for (int i=0;i<2;i++){
      float4 x = *(const float4*)(src + i*8);
      float4 y = *(const float4*)(src + i*8 + 4);
      uint4 u; u.x=pk2(x.x,x.y); u.y=pk2(x.z,x.w); u.z=pk2(y.x,y.y); u.w=pk2(y.z,y.w);
      *(uint4*)(arow + (((cb+i*8)*2) ^ swz)) = u;
    }
    #pragma unroll
    for (int i=0;i<2;i++){
      float4 x = *(const float4*)(s2 + i*8);
      float4 y = *(const float4*)(s2 + i*8 + 4);
      uint4 u; u.x=pk2(x.x,x.y); u.y=pk2(x.z,x.w); u.z=pk2(y.x,y.y); u.w=pk2(y.z,y.w);
      *(uint4*)(arow + (((256+cb+i*8)*2) ^ swz)) = u;
    }
  }
  __syncthreads();

  unsigned swzL = (unsigned)((l15&7)<<4);
  const char* pa0 = A + (wr*32 + l15)*1024;
  const char* pa1 = pa0 + 16*1024;
  const unsigned short* wg0 = Wgt + (size_t)(wc*32 + l15)*512 + lg*8;
  const unsigned short* wc0 = Wct + (size_t)(wc*32 + l15)*512 + lg*8;

  f32x4 accg[2][2], accc[2][2];
  f32x4 zz = {0.f,0.f,0.f,0.f};
  #pragma unroll
  for (int ri=0;ri<2;ri++){ accg[ri][0]=zz; accg[ri][1]=zz; accc[ri][0]=zz; accc[ri][1]=zz; }

  for (int ks=0; ks<16; ++ks){
    int koff = (ks*64 + lg*16) ^ (int)swzL;
    bf16x8 a0 = *(const bf16x8*)(pa0 + koff);
    bf16x8 a1 = *(const bf16x8*)(pa1 + koff);
    int kw = ks*32;
    #pragma unroll
    for (int ct=0; ct<2; ++ct){
      bf16x8 b = *(const bf16x8*)(wg0 + ct*16*512 + kw);
      accg[0][ct] = __builtin_amdgcn_mfma_f32_16x16x32_bf16(a0, b, accg[0][ct], 0,0,0);
      accg[1][ct] = __builtin_amdgcn_mfma_f32_16x16x32_bf16(a1, b, accg[1][ct], 0,0,0);
    }
  }

  float bgv[2], bcv[2];
  #pragma unroll
  for (int ct=0;ct<2;ct++){ int c = wc*32+ct*16+l15; bgv[ct]=bg[c]; bcv[ct]=bc[c]; }
  #pragma unroll
  for (int ri=0;ri<2;ri++)
    #pragma unroll
    for (int ct=0;ct<2;ct++)
      #pragma unroll
      for (int j=0;j<4;j++)
        accg[ri][ct][j] = 1.f/(1.f + __expf(-(accg[ri][ct][j] + bgv[ct])));

  for (int ks=0; ks<16; ++ks){
    int koff = (ks*64 + lg*16) ^ (int)swzL;
    bf16x8 a0 = *(const bf16x8*)(pa0 + koff);
    bf16x8 a1 = *(const bf16x8*)(pa1 + koff);
    int kw = ks*32;
    #pragma unroll
    for (int ct=0; ct<2; ++ct){
      bf16x8 b = *(const bf16x8*)(wc0 + ct*16*512 + kw);
      accc[0][ct] = __builtin_amdgcn_mfma_f32_16x16x32_bf16(a0, b, accc[0][ct], 0,0,0);
      accc[1][ct] = __builtin_amdgcn_mfma_f32_16x16x32_bf16(a1, b, accc[1][ct], 0,0,0);
    }
  }

  #pragma unroll
  for (int ct=0; ct<2; ++ct){
    #pragma unroll
    for (int ri=0; ri<2; ++ri){
      #pragma unroll
      for (int j=0;j<4;j++){
        int row = wr*32 + ri*16 + lg*4 + j;
        int col = wc*32 + ct*16 + l15;
        int e = e0 + row;
        float prevv = prevn[(size_t)e*DD + col];
        float fr = accg[ri][ct][j];
        float cand = fmaxf(accc[ri][ct][j] + bcv[ct], 0.f);
        out[(size_t)e*DD + col] = fr*prevv + (1.f-fr)*cand;
      }
    }
  }
}

extern "C" void kernel_launch(void* const* d_in, const int* in_sizes, int n_in,
                              void* d_out, int out_size, void* d_ws, size_t ws_size,
                              hipStream_t stream){
  const float* expr = (const float*)d_in[0];
  const float* sym  = (const float*)d_in[1];
  const float* prevn= (const float*)d_in[2];
  const float* Wg1 = (const float*)d_in[3];
  const float* bg1 = (const float*)d_in[4];
  const float* Wc1 = (const float*)d_in[5];
  const float* bc1 = (const float*)d_in[6];
  const float* Wg2 = (const float*)d_in[7];
  const float* bg2 = (const float*)d_in[8];
  const float* Wc2 = (const float*)d_in[9];
  const float* bc2 = (const float*)d_in[10];
  const int* aei = (const int*)d_in[11];
  const int* ati = (const int*)d_in[12];
  const int* asi = (const int*)d_in[13];
  float* outp = (float*)d_out;

  char* wsb = (char*)d_ws;
  int* winner = (int*)(wsb + WS_WINNER);
  char* wtsw = wsb + WS_WTSW;
  unsigned short* wtlin = (unsigned short*)(wsb + WS_WTLIN);
  unsigned short* symgc = (unsigned short*)(wsb + WS_SYMGC);

  hipMemsetAsync(winner, 0xFF, NSLOT*sizeof(int), stream);
  k_wt<<<256, 256, 0, stream>>>(Wg1, Wc1, Wg2, Wc2, wtsw, wtlin);
  k_winner<<<NAPP/256, 256, 0, stream>>>(aei, ati, winner);
  k_syms<<<NSYMP/64, 512, 0, stream>>>(sym, wtsw, symgc);
  k_gate1<<<NE, 256, 0, stream>>>(expr, wtsw, bg1, bc1, winner, asi, symgc, outp);
  k_gate2<<<NE/64, 1024, 0, stream>>>(prevn, outp, bg2, bc2,
                                      wtlin + 262144, wtlin + 393216, outp);
}